// Round 7
// baseline (302.402 us; speedup 1.0000x reference)
//
#include <hip/hip_runtime.h>
#include <stdint.h>

#define DD 2048
#define SS 2048
#define NB 2
#define NH 16
#define HDIM 128
#define MM (NB*SS)   // 4096 rows

typedef __attribute__((ext_vector_type(8))) short bf16x8;
typedef __attribute__((ext_vector_type(4))) float f32x4;
typedef __attribute__((ext_vector_type(4))) ushort u16x4;

__device__ __forceinline__ float fast_exp2(float x) {
  return __builtin_amdgcn_exp2f(x);   // v_exp_f32 (2^x natively)
}

__device__ __forceinline__ ushort f2bf(float f) {
  union { float f; uint32_t u; } v; v.f = f;
  uint32_t u = v.u;
  return (ushort)((u + 0x7fffu + ((u >> 16) & 1u)) >> 16);
}

__device__ __forceinline__ void gld_lds16(const ushort* g, ushort* l) {
  __builtin_amdgcn_global_load_lds(
      (const __attribute__((address_space(1))) void*)g,
      (__attribute__((address_space(3))) void*)l, 16, 0, 0);
}

// ---------------- fp32 -> bf16 conversion of x and the 4 weights -------------
__global__ __launch_bounds__(256) void cvt_all(
    const float* __restrict__ x, const float* __restrict__ wq,
    const float* __restrict__ wk, const float* __restrict__ wv,
    const float* __restrict__ wo, ushort* __restrict__ dst)
{
  int i8 = blockIdx.x * 256 + threadIdx.x;   // one 8-float chunk per thread
  const int X8 = MM * DD / 8;                // 1,048,576
  const int W8 = DD * DD / 8;                // 524,288
  const float* src; int off;
  if (i8 < X8)            { src = x;  off = i8; }
  else if (i8 < X8 +   W8){ src = wq; off = i8 - X8; }
  else if (i8 < X8 + 2*W8){ src = wk; off = i8 - (X8 +   W8); }
  else if (i8 < X8 + 3*W8){ src = wv; off = i8 - (X8 + 2*W8); }
  else                    { src = wo; off = i8 - (X8 + 3*W8); }
  const float4* p = (const float4*)src;
  float4 a = p[(long)off*2], b = p[(long)off*2 + 1];
  bf16x8 o;
  o[0]=(short)f2bf(a.x); o[1]=(short)f2bf(a.y); o[2]=(short)f2bf(a.z); o[3]=(short)f2bf(a.w);
  o[4]=(short)f2bf(b.x); o[5]=(short)f2bf(b.y); o[6]=(short)f2bf(b.z); o[7]=(short)f2bf(b.w);
  *(bf16x8*)(dst + (long)i8*8) = o;
}

// ---- m201-geometry GEMM: 256x256 tile, BK=64, 8 waves (2Mx4N), dbuf --------
// Per-wave output 128x64 (acc 8x4), 16-MFMA phases, quadrant order
// Q00->Q10->Q11->Q01 (each phase reloads one operand half: 24 ds_read/K-tile).
// All 8 stage-loads of tile kt+1 issued in phases 0-1; vmcnt(0) at boundary.
// MODE 0: QKV fused (N=6144, 384 blocks): Q scaled, K, V transposed.
// MODE 1: O-proj (N=2048, 128 blocks): f32 out.
template<int MODE>
__global__ __launch_bounds__(512, 2) void gemm256(
    const ushort* __restrict__ A, const ushort* __restrict__ Bt,
    ushort* __restrict__ Qo, ushort* __restrict__ Ko, ushort* __restrict__ Vt,
    float* __restrict__ Cf)
{
  __shared__ ushort lds[65536];   // 128 KB: A dbuf 2x32KB | B dbuf 2x32KB
  const int t = threadIdx.x;
  const int bid = blockIdx.x;
  const int xcd = bid & 7, local = bid >> 3;
  const int NBX = (MODE == 0) ? 3 : 1;       // n-tiles per XCD chunk
  const int bm = local / NBX;
  const int bn = xcd * NBX + (local - bm * NBX);
  const int lane = t & 63, w = t >> 6;
  const int wr = w >> 2;                     // 0..1 : 128-row half
  const int wcn = w & 3;                     // 0..3 : 64-col group
  const int lr = lane & 15, lg = lane >> 4;

  // staging map (identical for A and B: both tiles are 256 rows x 64 cols)
  // LDS slot 'slot' of a row holds global chunk slot^(row&7)  (T2 swizzle)
  int aoff[4], aldo[4];
#pragma unroll
  for (int i = 0; i < 4; ++i) {
    int c = i*512 + t, row = c >> 3, slot = c & 7, gc = slot ^ (row & 7);
    aoff[i] = row*DD + gc*8; aldo[i] = c*8;
  }
  const ushort* Ab = A  + (long)(bm*256) * DD;
  const ushort* Bb = Bt + (long)(bn*256) * DD;

#define STG_A(P, KT, D) do { const ushort* g_ = Ab + (KT)*64;              \
    ushort* l_ = lds + (D)*16384;                                          \
    gld_lds16(g_ + aoff[2*(P)],   l_ + aldo[2*(P)]);                       \
    gld_lds16(g_ + aoff[2*(P)+1], l_ + aldo[2*(P)+1]); } while (0)
#define STG_B(P, KT, D) do { const ushort* g_ = Bb + (KT)*64;              \
    ushort* l_ = lds + 32768 + (D)*16384;                                  \
    gld_lds16(g_ + aoff[2*(P)],   l_ + aldo[2*(P)]);                       \
    gld_lds16(g_ + aoff[2*(P)+1], l_ + aldo[2*(P)+1]); } while (0)
#define LDA(dst, MH, m, ks) { int r_ = wr*128 + (MH)*64 + (m)*16 + lr;     \
    (dst) = *(const bf16x8*)(ab + r_*128 + ((((ks)*4+lg)^(r_&7))*16)); }
#define LDB(dst, NH_, n, ks) { int r_ = wcn*64 + (NH_)*32 + (n)*16 + lr;   \
    (dst) = *(const bf16x8*)(bb + r_*128 + ((((ks)*4+lg)^(r_&7))*16)); }
#define MFMA16(AV, BV, MB, NBASE) do {                                     \
    __builtin_amdgcn_s_setprio(1);                                         \
    _Pragma("unroll") for (int ks = 0; ks < 2; ++ks)                       \
    _Pragma("unroll") for (int m = 0; m < 4; ++m)                          \
    _Pragma("unroll") for (int n = 0; n < 2; ++n)                          \
      acc[(MB)+m][(NBASE)+n] = __builtin_amdgcn_mfma_f32_16x16x32_bf16(    \
          AV[m][ks], BV[n][ks], acc[(MB)+m][(NBASE)+n], 0, 0, 0);          \
    __builtin_amdgcn_s_setprio(0); } while (0)
#define SB  __builtin_amdgcn_sched_barrier(0)
#define BAR __builtin_amdgcn_s_barrier()
#define LGKM0 asm volatile("s_waitcnt lgkmcnt(0)" ::: "memory")

  f32x4 acc[8][4] = {};
  const int T = DD / 64;                     // 32 K-tiles

  // prologue: stage tile 0 into dbuf0, drain, barrier
  STG_A(0, 0, 0); STG_A(1, 0, 0); STG_B(0, 0, 0); STG_B(1, 0, 0);
  asm volatile("s_waitcnt vmcnt(0)" ::: "memory");
  SB; BAR; SB;

  for (int kt = 0; kt < T; ++kt) {
    const char* ab = (const char*)lds + (kt & 1) * 32768;
    const char* bb = (const char*)lds + 65536 + (kt & 1) * 32768;
    const int wd = (kt + 1) & 1;
    const bool st = (kt + 1 < T);
    bf16x8 af0[4][2], af1[4][2], bf[2][2];
    // ---- P0: quadrant (mh0, nh0); stage A of tile kt+1 ----
    LDA(af0[0][0],0,0,0); LDA(af0[1][0],0,1,0); LDA(af0[2][0],0,2,0); LDA(af0[3][0],0,3,0);
    LDA(af0[0][1],0,0,1); LDA(af0[1][1],0,1,1); LDA(af0[2][1],0,2,1); LDA(af0[3][1],0,3,1);
    LDB(bf[0][0],0,0,0);  LDB(bf[1][0],0,1,0);
    LDB(bf[0][1],0,0,1);  LDB(bf[1][1],0,1,1);
    if (st) { STG_A(0, kt+1, wd); STG_A(1, kt+1, wd); }
    SB; BAR; LGKM0; SB;
    MFMA16(af0, bf, 0, 0);
    SB; BAR; SB;
    // ---- P1: quadrant (mh1, nh0); stage B of tile kt+1 ----
    LDA(af1[0][0],1,0,0); LDA(af1[1][0],1,1,0); LDA(af1[2][0],1,2,0); LDA(af1[3][0],1,3,0);
    LDA(af1[0][1],1,0,1); LDA(af1[1][1],1,1,1); LDA(af1[2][1],1,2,1); LDA(af1[3][1],1,3,1);
    if (st) { STG_B(0, kt+1, wd); STG_B(1, kt+1, wd); }
    SB; BAR; LGKM0; SB;
    MFMA16(af1, bf, 4, 0);
    SB; BAR; SB;
    // ---- P2: quadrant (mh1, nh1); reload B only ----
    LDB(bf[0][0],1,0,0);  LDB(bf[1][0],1,1,0);
    LDB(bf[0][1],1,0,1);  LDB(bf[1][1],1,1,1);
    SB; BAR; LGKM0; SB;
    MFMA16(af1, bf, 4, 2);
    SB; BAR; SB;
    // ---- P3: quadrant (mh0, nh1); no ds_read; boundary vmcnt ----
    if (st) { asm volatile("s_waitcnt vmcnt(0)" ::: "memory"); }
    SB; BAR; SB;
    MFMA16(af0, bf, 0, 2);
    SB; BAR; SB;
  }
#undef STG_A
#undef STG_B
#undef LDA
#undef LDB
#undef MFMA16
#undef SB
#undef BAR
#undef LGKM0

  // epilogue: C/D layout col=lane&15, row=(lane>>4)*4+j
  const int crb = bm*256 + wr*128 + lg*4;
  if (MODE == 0) {
    const int region = bn >> 3;              // 0=Q, 1=K, 2=V (8 tiles each)
    const int ccb = (bn & 7)*256 + wcn*64 + lr;
    if (region < 2) {
      const float scale = (region == 0) ? (0.08838834764831845f * 1.4426950408889634f) : 1.0f;
      ushort* C = (region == 0) ? Qo : Ko;
#pragma unroll
      for (int mh = 0; mh < 2; ++mh)
#pragma unroll
        for (int m = 0; m < 4; ++m)
#pragma unroll
          for (int nh = 0; nh < 2; ++nh)
#pragma unroll
            for (int n = 0; n < 2; ++n)
#pragma unroll
              for (int j = 0; j < 4; ++j)
                C[(long)(crb + mh*64 + m*16 + j) * DD + (ccb + nh*32 + n*16)] =
                    f2bf(acc[mh*4+m][nh*2+n][j] * scale);
    } else {
      // V transposed: Vt[(b*NH+h)*HDIM + d][s]; 4 j-rows = 4 contiguous s
#pragma unroll
      for (int mh = 0; mh < 2; ++mh)
#pragma unroll
        for (int m = 0; m < 4; ++m) {
          int sg = crb + mh*64 + m*16;
          int b2 = sg >> 11, s2 = sg & 2047;
#pragma unroll
          for (int nh = 0; nh < 2; ++nh)
#pragma unroll
            for (int n = 0; n < 2; ++n) {
              int colv = ccb + nh*32 + n*16;
              int h2 = colv >> 7, d2 = colv & 127;
              u16x4 pk;
              pk[0] = f2bf(acc[mh*4+m][nh*2+n][0]); pk[1] = f2bf(acc[mh*4+m][nh*2+n][1]);
              pk[2] = f2bf(acc[mh*4+m][nh*2+n][2]); pk[3] = f2bf(acc[mh*4+m][nh*2+n][3]);
              *(u16x4*)(Vt + ((long)((b2*NH + h2)*HDIM + d2)) * SS + s2) = pk;
            }
        }
    }
  } else {
    const int ccb = bn*256 + wcn*64 + lr;
#pragma unroll
    for (int mh = 0; mh < 2; ++mh)
#pragma unroll
      for (int m = 0; m < 4; ++m)
#pragma unroll
        for (int nh = 0; nh < 2; ++nh)
#pragma unroll
          for (int n = 0; n < 2; ++n)
#pragma unroll
            for (int j = 0; j < 4; ++j)
              Cf[(long)(crb + mh*64 + m*16 + j) * DD + (ccb + nh*32 + n*16)] =
                  acc[mh*4+m][nh*2+n][j];
  }
}

// ---------------- causal flash attention (8 waves x 16 q-rows) ---------------
// K staged via global_load_lds with pre-swizzled source (read XOR (r&7)<<4);
// V already transposed in global -> staged the same way; no scalar transpose.
__global__ __launch_bounds__(512, 4) void attn_fwd(
    const ushort* __restrict__ Qb, const ushort* __restrict__ Kb,
    const ushort* __restrict__ Vtg, ushort* __restrict__ Ob)
{
  __shared__ ushort Ks[64*128];     // [k][d] rows 256B, XOR-swizzled chunks
  __shared__ ushort Vs[128*64];     // [d][k] rows 128B, XOR-swizzled chunks
  __shared__ ushort Ps[8*16*72];    // per-wave P [16][64], padded stride 72

  const int bid = blockIdx.x;
  const int qt = 15 - (bid >> 5);   // LPT: heaviest q-tiles first
  const int bh = bid & 31;
  const int b = bh >> 4, h = bh & 15;
  const int t = threadIdx.x;
  const int lane = t & 63;
  const int wq = t >> 6;            // 0..7
  const int lr = lane & 15, lg = lane >> 4;

  const int qbase = qt * 128;
  const long rowQ = (long)(b * SS + qbase + wq * 16);

  bf16x8 qf[4];                     // Q rows of this wave, pre-scaled
#pragma unroll
  for (int c = 0; c < 4; ++c)
    qf[c] = *(const bf16x8*)(Qb + (rowQ + lr) * DD + h*HDIM + c*32 + lg*8);

  f32x4 accO[8] = {};
  float mrow[4], lrow[4];
#pragma unroll
  for (int j = 0; j < 4; ++j) { mrow[j] = -1e30f; lrow[j] = 0.f; }

  // K staging: 1024 16B-chunks; thread t owns chunks t and 512+t
  const ushort* Kgb = Kb + (long)(b * SS) * DD + h * HDIM;
  const int kr0 = t >> 4, kr1 = 32 + (t >> 4), kci = t & 15;
  const ushort* gk0 = Kgb + (long)kr0 * DD + (kci ^ (kr0 & 7)) * 8;
  const ushort* gk1 = Kgb + (long)kr1 * DD + (kci ^ (kr1 & 7)) * 8;
  ushort* lk0 = Ks + t*8;
  ushort* lk1 = Ks + 4096 + t*8;

  // V^T staging: rows d (128B), 8 chunks each
  const ushort* Vgb = Vtg + (long)(bh * HDIM) * SS;
  const int vd0 = t >> 3, vd1 = 64 + (t >> 3), vci = t & 7;
  const ushort* gv0 = Vgb + (long)vd0 * SS + (vci ^ (vd0 & 7)) * 8;
  const ushort* gv1 = Vgb + (long)vd1 * SS + (vci ^ (vd1 & 7)) * 8;
  ushort* lv0 = Vs + t*8;
  ushort* lv1 = Vs + 4096 + t*8;

  const int ktmax = 2*qt + 1;
  const int qminw = qbase + wq*16;        // wave's FIRST q-row (mask trigger)
  const int qmaxw = qminw + 15;           // wave's last q-row (skip test)
  ushort* myP = Ps + wq * (16*72);

  for (int kt = 0; kt <= ktmax; ++kt) {
    const int k0 = kt * 64;
    gld_lds16(gk0, lk0); gld_lds16(gk1, lk1);
    gld_lds16(gv0, lv0); gld_lds16(gv1, lv1);
    gk0 += (long)64 * DD; gk1 += (long)64 * DD;
    gv0 += 64; gv1 += 64;
    __syncthreads();                 // drains vmcnt -> LDS tiles ready

    if (k0 <= qmaxw) {
      f32x4 sc[4] = {};
#pragma unroll
      for (int n = 0; n < 4; ++n) {  // S = Q K^T (this wave's 16 q-rows)
        int r = n*16 + lr;
        int swz = (r & 7) << 4;
#pragma unroll
        for (int c = 0; c < 4; ++c) {
          bf16x8 kf = *(const bf16x8*)((const char*)Ks + ((r*256 + c*64 + lg*16) ^ swz));
          sc[n] = __builtin_amdgcn_mfma_f32_16x16x32_bf16(qf[c], kf, sc[n], 0,0,0);
        }
      }
      if (k0 + 63 > qminw) {         // tile has keys beyond wave's FIRST row
#pragma unroll
        for (int n = 0; n < 4; ++n)
#pragma unroll
          for (int j = 0; j < 4; ++j) {
            int kpos = k0 + n*16 + lr;
            int qpos = qminw + lg*4 + j;
            if (kpos > qpos) sc[n][j] = -1e30f;
          }
      }
      float al[4];
#pragma unroll
      for (int j = 0; j < 4; ++j) {  // online softmax in log2 domain
        float tm = fmaxf(fmaxf(sc[0][j], sc[1][j]), fmaxf(sc[2][j], sc[3][j]));
#pragma unroll
        for (int off = 1; off < 16; off <<= 1) tm = fmaxf(tm, __shfl_xor(tm, off));
        float mn = fmaxf(mrow[j], tm);
        float a = fast_exp2(mrow[j] - mn);
        mrow[j] = mn;
        float ts = 0.f;
#pragma unroll
        for (int n = 0; n < 4; ++n) {
          float p = fast_exp2(sc[n][j] - mn);
          sc[n][j] = p; ts += p;
        }
#pragma unroll
        for (int off = 1; off < 16; off <<= 1) ts += __shfl_xor(ts, off);
        lrow[j] = lrow[j] * a + ts;
        al[j] = a;
      }
#pragma unroll
      for (int dg = 0; dg < 8; ++dg) {
        f32x4 v = accO[dg];
        v[0] *= al[0]; v[1] *= al[1]; v[2] *= al[2]; v[3] *= al[3];
        accO[dg] = v;
      }
#pragma unroll
      for (int n = 0; n < 4; ++n)    // P -> per-wave LDS (D-layout -> A-layout)
#pragma unroll
        for (int j = 0; j < 4; ++j)
          myP[(lg*4 + j)*72 + n*16 + lr] = f2bf(sc[n][j]);
      bf16x8 pa0 = *(const bf16x8*)(myP + lr*72 + lg*8);
      bf16x8 pa1 = *(const bf16x8*)(myP + lr*72 + 32 + lg*8);
#pragma unroll
      for (int dg = 0; dg < 8; ++dg) {   // O += P V
        int d = dg*16 + lr;
        int vswz = (d & 7) << 4;
        bf16x8 v0 = *(const bf16x8*)((const char*)Vs + ((d*128 + lg*16) ^ vswz));
        bf16x8 v1 = *(const bf16x8*)((const char*)Vs + ((d*128 + 64 + lg*16) ^ vswz));
        accO[dg] = __builtin_amdgcn_mfma_f32_16x16x32_bf16(pa0, v0, accO[dg], 0,0,0);
        accO[dg] = __builtin_amdgcn_mfma_f32_16x16x32_bf16(pa1, v1, accO[dg], 0,0,0);
      }
    }
    __syncthreads();                 // reads done before restage
  }

  float inv[4];
#pragma unroll
  for (int j = 0; j < 4; ++j) inv[j] = 1.0f / lrow[j];
  ushort* Og = Ob + rowQ * DD + h * HDIM;
#pragma unroll
  for (int dg = 0; dg < 8; ++dg)
#pragma unroll
    for (int j = 0; j < 4; ++j)
      Og[(long)(lg*4 + j) * DD + dg*16 + lr] = f2bf(accO[dg][j] * inv[j]);
}

// ---------------- launch ----------------------------------------------------
extern "C" void kernel_launch(void* const* d_in, const int* in_sizes, int n_in,
                              void* d_out, int out_size, void* d_ws, size_t ws_size,
                              hipStream_t stream) {
  const float* x  = (const float*)d_in[0];
  const float* Wq = (const float*)d_in[1];
  const float* Wk = (const float*)d_in[2];
  const float* Wv = (const float*)d_in[3];
  const float* Wo = (const float*)d_in[4];

  ushort* ws  = (ushort*)d_ws;
  ushort* xb  = ws;                         // x bf16; later reused as attn-out
  ushort* wqb = ws  + (long)MM*DD;          // wq/wk/wv contiguous = fused Bt
  ushort* wkb = wqb + (long)DD*DD;
  ushort* wvb = wkb + (long)DD*DD;
  ushort* wob = wvb + (long)DD*DD;
  ushort* Qb  = wob + (long)DD*DD;
  ushort* Kb  = Qb  + (long)MM*DD;
  ushort* Vtg = Kb  + (long)MM*DD;          // V stored transposed [bh*128+d][s]
  (void)wkb; (void)wvb;

  const int CVT_BLOCKS = (MM*DD + 4*DD*DD) / 8 / 256;   // 12288
  cvt_all<<<CVT_BLOCKS, 256, 0, stream>>>(x, Wq, Wk, Wv, Wo, ws);

  gemm256<0><<<384, 512, 0, stream>>>(xb, wqb, Qb, Kb, Vtg, nullptr);

  attn_fwd<<<512, 512, 0, stream>>>(Qb, Kb, Vtg, xb);   // attn out -> xb

  gemm256<1><<<128, 512, 0, stream>>>(xb, wob, nullptr, nullptr, nullptr,
                                      (float*)d_out);
}

// Round 8
// 297.037 us; speedup vs baseline: 1.0181x; 1.0181x over previous
//
#include <hip/hip_runtime.h>
#include <stdint.h>

#define DD 2048
#define SS 2048
#define NB 2
#define NH 16
#define HDIM 128
#define MM (NB*SS)   // 4096 rows

typedef __attribute__((ext_vector_type(8))) short bf16x8;
typedef __attribute__((ext_vector_type(4))) float f32x4;
typedef __attribute__((ext_vector_type(4))) ushort u16x4;

__device__ __forceinline__ float fast_exp2(float x) {
  return __builtin_amdgcn_exp2f(x);   // v_exp_f32 (2^x natively)
}

__device__ __forceinline__ ushort f2bf(float f) {
  union { float f; uint32_t u; } v; v.f = f;
  uint32_t u = v.u;
  return (ushort)((u + 0x7fffu + ((u >> 16) & 1u)) >> 16);
}

__device__ __forceinline__ void gld_lds16(const ushort* g, ushort* l) {
  __builtin_amdgcn_global_load_lds(
      (const __attribute__((address_space(1))) void*)g,
      (__attribute__((address_space(3))) void*)l, 16, 0, 0);
}

// ---------------- fp32 -> bf16 conversion of x and the 4 weights -------------
__global__ __launch_bounds__(256) void cvt_all(
    const float* __restrict__ x, const float* __restrict__ wq,
    const float* __restrict__ wk, const float* __restrict__ wv,
    const float* __restrict__ wo, ushort* __restrict__ dst)
{
  int i8 = blockIdx.x * 256 + threadIdx.x;   // one 8-float chunk per thread
  const int X8 = MM * DD / 8;                // 1,048,576
  const int W8 = DD * DD / 8;                // 524,288
  const float* src; int off;
  if (i8 < X8)            { src = x;  off = i8; }
  else if (i8 < X8 +   W8){ src = wq; off = i8 - X8; }
  else if (i8 < X8 + 2*W8){ src = wk; off = i8 - (X8 +   W8); }
  else if (i8 < X8 + 3*W8){ src = wv; off = i8 - (X8 + 2*W8); }
  else                    { src = wo; off = i8 - (X8 + 3*W8); }
  const float4* p = (const float4*)src;
  float4 a = p[(long)off*2], b = p[(long)off*2 + 1];
  bf16x8 o;
  o[0]=(short)f2bf(a.x); o[1]=(short)f2bf(a.y); o[2]=(short)f2bf(a.z); o[3]=(short)f2bf(a.w);
  o[4]=(short)f2bf(b.x); o[5]=(short)f2bf(b.y); o[6]=(short)f2bf(b.z); o[7]=(short)f2bf(b.w);
  *(bf16x8*)(dst + (long)i8*8) = o;
}

// ---------------- fused QKV GEMM (m97 structure, 128x128, BK=32) -------------
// 16 KB LDS + 104 VGPR -> ~4 blocks/CU: cross-block overlap hides barrier
// drains (m114). Block mapping: per XCD a 6-bn-wide B panel (3.1 MB, stays
// L2-resident); 6 consecutive blocks share one x panel (L2 hit).
__global__ __launch_bounds__(256, 4) void gemm_qkv(
    const ushort* __restrict__ A, const ushort* __restrict__ Bt,
    ushort* __restrict__ Qo, ushort* __restrict__ Ko, ushort* __restrict__ Vt)
{
  __shared__ ushort As[4096];
  __shared__ ushort Bs[4096];
  const int bid = blockIdx.x;                // 1536 blocks
  const int l = bid >> 3;                    // 0..191
  const int bm = l / 6;                      // 0..31
  const int bn = (bid & 7) * 6 + (l - bm * 6);   // 0..47, XCD-chunked
  const int t = threadIdx.x;
  const int lane = t & 63;
  const int wr = t >> 7, wc = (t >> 6) & 1;

  f32x4 acc[4][4] = {};

  const ushort* ga0 = A  + (long)(bm*128 + (t>>2)) * DD + (t&3)*8;
  const ushort* ga1 = ga0 + (long)64 * DD;
  const ushort* gb0 = Bt + (long)(bn*128 + (t>>2)) * DD + (t&3)*8;
  const ushort* gb1 = gb0 + (long)64 * DD;
  ushort* la0 = As + t*8;  ushort* la1 = As + 2048 + t*8;
  ushort* lb0 = Bs + t*8;  ushort* lb1 = Bs + 2048 + t*8;

  const ushort* pa = As + (wr*64 + (lane & 15)) * 32 + (lane >> 4) * 8;
  const ushort* pb = Bs + (wc*64 + (lane & 15)) * 32 + (lane >> 4) * 8;

  for (int kt = 0; kt < DD; kt += 32) {
    gld_lds16(ga0, la0); gld_lds16(ga1, la1);
    gld_lds16(gb0, lb0); gld_lds16(gb1, lb1);
    ga0 += 32; ga1 += 32; gb0 += 32; gb1 += 32;
    __syncthreads();
    bf16x8 af[4], bfr[4];
#pragma unroll
    for (int m = 0; m < 4; ++m) af[m]  = *(const bf16x8*)(pa + m*16*32);
#pragma unroll
    for (int n = 0; n < 4; ++n) bfr[n] = *(const bf16x8*)(pb + n*16*32);
#pragma unroll
    for (int m = 0; m < 4; ++m)
#pragma unroll
      for (int n = 0; n < 4; ++n)
        acc[m][n] = __builtin_amdgcn_mfma_f32_16x16x32_bf16(af[m], bfr[n], acc[m][n], 0, 0, 0);
    __syncthreads();
  }

  const int region = bn >> 4;                 // 0=Q, 1=K, 2=V
  const int bn2 = bn & 15;
  const int cr = bm*128 + wr*64 + (lane >> 4) * 4;   // row base (j=0)
  const int cc = bn2*128 + wc*64 + (lane & 15);      // col within region

  if (region < 2) {
    // Q gets 1/sqrt(128)*log2(e) folded in (softmax uses exp2)
    const float scale = (region == 0) ? (0.08838834764831845f * 1.4426950408889634f) : 1.0f;
    ushort* C = (region == 0) ? Qo : Ko;
#pragma unroll
    for (int m = 0; m < 4; ++m)
#pragma unroll
      for (int n = 0; n < 4; ++n)
#pragma unroll
        for (int j = 0; j < 4; ++j)
          C[(long)(cr + m*16 + j) * DD + (cc + n*16)] = f2bf(acc[m][n][j] * scale);
  } else {
    // V transposed: Vt[(b*NH+h)*HDIM + d][s]; the 4 j-rows are 4 contiguous s
#pragma unroll
    for (int m = 0; m < 4; ++m) {
      int sg = cr + m*16;
      int b2 = sg >> 11, s2 = sg & 2047;
#pragma unroll
      for (int n = 0; n < 4; ++n) {
        int colv = cc + n*16;
        int h2 = colv >> 7, d2 = colv & 127;
        u16x4 pk;
        pk[0] = f2bf(acc[m][n][0]); pk[1] = f2bf(acc[m][n][1]);
        pk[2] = f2bf(acc[m][n][2]); pk[3] = f2bf(acc[m][n][3]);
        *(u16x4*)(Vt + ((long)((b2*NH + h2)*HDIM + d2)) * SS + s2) = pk;
      }
    }
  }
}

// ---------------- O-projection GEMM (same structure, f32 out) ----------------
__global__ __launch_bounds__(256, 4) void gemm_bt_f32(
    const ushort* __restrict__ A, const ushort* __restrict__ Bt,
    float* __restrict__ C)
{
  __shared__ ushort As[4096];
  __shared__ ushort Bs[4096];
  const int bid = blockIdx.x;                // 512 blocks
  const int l = bid >> 3;                    // 0..63
  const int bm = l >> 1;                     // 0..31
  const int bn = (bid & 7) * 2 + (l & 1);    // 0..15, XCD-chunked
  const int t = threadIdx.x;
  const int lane = t & 63;
  const int wr = t >> 7, wc = (t >> 6) & 1;

  f32x4 acc[4][4] = {};

  const ushort* ga0 = A  + (long)(bm*128 + (t>>2)) * DD + (t&3)*8;
  const ushort* ga1 = ga0 + (long)64 * DD;
  const ushort* gb0 = Bt + (long)(bn*128 + (t>>2)) * DD + (t&3)*8;
  const ushort* gb1 = gb0 + (long)64 * DD;
  ushort* la0 = As + t*8;  ushort* la1 = As + 2048 + t*8;
  ushort* lb0 = Bs + t*8;  ushort* lb1 = Bs + 2048 + t*8;

  const ushort* pa = As + (wr*64 + (lane & 15)) * 32 + (lane >> 4) * 8;
  const ushort* pb = Bs + (wc*64 + (lane & 15)) * 32 + (lane >> 4) * 8;

  for (int kt = 0; kt < DD; kt += 32) {
    gld_lds16(ga0, la0); gld_lds16(ga1, la1);
    gld_lds16(gb0, lb0); gld_lds16(gb1, lb1);
    ga0 += 32; ga1 += 32; gb0 += 32; gb1 += 32;
    __syncthreads();
    bf16x8 af[4], bfr[4];
#pragma unroll
    for (int m = 0; m < 4; ++m) af[m]  = *(const bf16x8*)(pa + m*16*32);
#pragma unroll
    for (int n = 0; n < 4; ++n) bfr[n] = *(const bf16x8*)(pb + n*16*32);
#pragma unroll
    for (int m = 0; m < 4; ++m)
#pragma unroll
      for (int n = 0; n < 4; ++n)
        acc[m][n] = __builtin_amdgcn_mfma_f32_16x16x32_bf16(af[m], bfr[n], acc[m][n], 0, 0, 0);
    __syncthreads();
  }

  int cr = bm*128 + wr*64 + (lane >> 4) * 4;
  int cc = bn*128 + wc*64 + (lane & 15);
#pragma unroll
  for (int m = 0; m < 4; ++m)
#pragma unroll
    for (int n = 0; n < 4; ++n)
#pragma unroll
      for (int j = 0; j < 4; ++j)
        C[(long)(cr + m*16 + j) * DD + (cc + n*16)] = acc[m][n][j];
}

// ---------------- causal flash attention (8 waves x 16 q-rows) ---------------
// K staged via global_load_lds with pre-swizzled source (read XOR (r&7)<<4);
// V already transposed in global -> staged the same way; no scalar transpose.
__global__ __launch_bounds__(512, 4) void attn_fwd(
    const ushort* __restrict__ Qb, const ushort* __restrict__ Kb,
    const ushort* __restrict__ Vtg, ushort* __restrict__ Ob)
{
  __shared__ ushort Ks[64*128];     // [k][d] rows 256B, XOR-swizzled chunks
  __shared__ ushort Vs[128*64];     // [d][k] rows 128B, XOR-swizzled chunks
  __shared__ ushort Ps[8*16*72];    // per-wave P [16][64], padded stride 72

  const int bid = blockIdx.x;
  const int qt = 15 - (bid >> 5);   // LPT: heaviest q-tiles first
  const int bh = bid & 31;
  const int b = bh >> 4, h = bh & 15;
  const int t = threadIdx.x;
  const int lane = t & 63;
  const int wq = t >> 6;            // 0..7
  const int lr = lane & 15, lg = lane >> 4;

  const int qbase = qt * 128;
  const long rowQ = (long)(b * SS + qbase + wq * 16);

  bf16x8 qf[4];                     // Q rows of this wave, pre-scaled
#pragma unroll
  for (int c = 0; c < 4; ++c)
    qf[c] = *(const bf16x8*)(Qb + (rowQ + lr) * DD + h*HDIM + c*32 + lg*8);

  f32x4 accO[8] = {};
  float mrow[4], lrow[4];
#pragma unroll
  for (int j = 0; j < 4; ++j) { mrow[j] = -1e30f; lrow[j] = 0.f; }

  // K staging: 1024 16B-chunks; thread t owns chunks t and 512+t
  const ushort* Kgb = Kb + (long)(b * SS) * DD + h * HDIM;
  const int kr0 = t >> 4, kr1 = 32 + (t >> 4), kci = t & 15;
  const ushort* gk0 = Kgb + (long)kr0 * DD + (kci ^ (kr0 & 7)) * 8;
  const ushort* gk1 = Kgb + (long)kr1 * DD + (kci ^ (kr1 & 7)) * 8;
  ushort* lk0 = Ks + t*8;
  ushort* lk1 = Ks + 4096 + t*8;

  // V^T staging: rows d (128B), 8 chunks each
  const ushort* Vgb = Vtg + (long)(bh * HDIM) * SS;
  const int vd0 = t >> 3, vd1 = 64 + (t >> 3), vci = t & 7;
  const ushort* gv0 = Vgb + (long)vd0 * SS + (vci ^ (vd0 & 7)) * 8;
  const ushort* gv1 = Vgb + (long)vd1 * SS + (vci ^ (vd1 & 7)) * 8;
  ushort* lv0 = Vs + t*8;
  ushort* lv1 = Vs + 4096 + t*8;

  const int ktmax = 2*qt + 1;
  const int qminw = qbase + wq*16;        // wave's FIRST q-row (mask trigger)
  const int qmaxw = qminw + 15;           // wave's last q-row (skip test)
  ushort* myP = Ps + wq * (16*72);

  for (int kt = 0; kt <= ktmax; ++kt) {
    const int k0 = kt * 64;
    gld_lds16(gk0, lk0); gld_lds16(gk1, lk1);
    gld_lds16(gv0, lv0); gld_lds16(gv1, lv1);
    gk0 += (long)64 * DD; gk1 += (long)64 * DD;
    gv0 += 64; gv1 += 64;
    __syncthreads();                 // drains vmcnt -> LDS tiles ready

    if (k0 <= qmaxw) {
      f32x4 sc[4] = {};
#pragma unroll
      for (int n = 0; n < 4; ++n) {  // S = Q K^T (this wave's 16 q-rows)
        int r = n*16 + lr;
        int swz = (r & 7) << 4;
#pragma unroll
        for (int c = 0; c < 4; ++c) {
          bf16x8 kf = *(const bf16x8*)((const char*)Ks + ((r*256 + c*64 + lg*16) ^ swz));
          sc[n] = __builtin_amdgcn_mfma_f32_16x16x32_bf16(qf[c], kf, sc[n], 0,0,0);
        }
      }
      if (k0 + 63 > qminw) {         // tile has keys beyond wave's FIRST row
#pragma unroll
        for (int n = 0; n < 4; ++n)
#pragma unroll
          for (int j = 0; j < 4; ++j) {
            int kpos = k0 + n*16 + lr;
            int qpos = qminw + lg*4 + j;
            if (kpos > qpos) sc[n][j] = -1e30f;
          }
      }
      float al[4];
#pragma unroll
      for (int j = 0; j < 4; ++j) {  // online softmax in log2 domain
        float tm = fmaxf(fmaxf(sc[0][j], sc[1][j]), fmaxf(sc[2][j], sc[3][j]));
#pragma unroll
        for (int off = 1; off < 16; off <<= 1) tm = fmaxf(tm, __shfl_xor(tm, off));
        float mn = fmaxf(mrow[j], tm);
        float a = fast_exp2(mrow[j] - mn);
        mrow[j] = mn;
        float ts = 0.f;
#pragma unroll
        for (int n = 0; n < 4; ++n) {
          float p = fast_exp2(sc[n][j] - mn);
          sc[n][j] = p; ts += p;
        }
#pragma unroll
        for (int off = 1; off < 16; off <<= 1) ts += __shfl_xor(ts, off);
        lrow[j] = lrow[j] * a + ts;
        al[j] = a;
      }
#pragma unroll
      for (int dg = 0; dg < 8; ++dg) {
        f32x4 v = accO[dg];
        v[0] *= al[0]; v[1] *= al[1]; v[2] *= al[2]; v[3] *= al[3];
        accO[dg] = v;
      }
#pragma unroll
      for (int n = 0; n < 4; ++n)    // P -> per-wave LDS (D-layout -> A-layout)
#pragma unroll
        for (int j = 0; j < 4; ++j)
          myP[(lg*4 + j)*72 + n*16 + lr] = f2bf(sc[n][j]);
      bf16x8 pa0 = *(const bf16x8*)(myP + lr*72 + lg*8);
      bf16x8 pa1 = *(const bf16x8*)(myP + lr*72 + 32 + lg*8);
#pragma unroll
      for (int dg = 0; dg < 8; ++dg) {   // O += P V
        int d = dg*16 + lr;
        int vswz = (d & 7) << 4;
        bf16x8 v0 = *(const bf16x8*)((const char*)Vs + ((d*128 + lg*16) ^ vswz));
        bf16x8 v1 = *(const bf16x8*)((const char*)Vs + ((d*128 + 64 + lg*16) ^ vswz));
        accO[dg] = __builtin_amdgcn_mfma_f32_16x16x32_bf16(pa0, v0, accO[dg], 0,0,0);
        accO[dg] = __builtin_amdgcn_mfma_f32_16x16x32_bf16(pa1, v1, accO[dg], 0,0,0);
      }
    }
    __syncthreads();                 // reads done before restage
  }

  float inv[4];
#pragma unroll
  for (int j = 0; j < 4; ++j) inv[j] = 1.0f / lrow[j];
  ushort* Og = Ob + rowQ * DD + h * HDIM;
#pragma unroll
  for (int dg = 0; dg < 8; ++dg)
#pragma unroll
    for (int j = 0; j < 4; ++j)
      Og[(long)(lg*4 + j) * DD + dg*16 + lr] = f2bf(accO[dg][j] * inv[j]);
}

// ---------------- launch ----------------------------------------------------
extern "C" void kernel_launch(void* const* d_in, const int* in_sizes, int n_in,
                              void* d_out, int out_size, void* d_ws, size_t ws_size,
                              hipStream_t stream) {
  const float* x  = (const float*)d_in[0];
  const float* Wq = (const float*)d_in[1];
  const float* Wk = (const float*)d_in[2];
  const float* Wv = (const float*)d_in[3];
  const float* Wo = (const float*)d_in[4];

  ushort* ws  = (ushort*)d_ws;
  ushort* xb  = ws;                         // x bf16; later reused as attn-out
  ushort* wqb = ws  + (long)MM*DD;          // wq/wk/wv contiguous = fused Bt
  ushort* wkb = wqb + (long)DD*DD;
  ushort* wvb = wkb + (long)DD*DD;
  ushort* wob = wvb + (long)DD*DD;
  ushort* Qb  = wob + (long)DD*DD;
  ushort* Kb  = Qb  + (long)MM*DD;
  ushort* Vtg = Kb  + (long)MM*DD;          // V stored transposed [bh*128+d][s]
  (void)wkb; (void)wvb;

  const int CVT_BLOCKS = (MM*DD + 4*DD*DD) / 8 / 256;   // 12288
  cvt_all<<<CVT_BLOCKS, 256, 0, stream>>>(x, Wq, Wk, Wv, Wo, ws);

  gemm_qkv<<<1536, 256, 0, stream>>>(xb, wqb, Qb, Kb, Vtg);

  attn_fwd<<<512, 512, 0, stream>>>(Qb, Kb, Vtg, xb);   // attn out -> xb

  gemm_bt_f32<<<512, 256, 0, stream>>>(xb, wob, (float*)d_out);
}

// Round 9
// 274.791 us; speedup vs baseline: 1.1005x; 1.0810x over previous
//
#include <hip/hip_runtime.h>
#include <stdint.h>

#define DD 2048
#define SS 2048
#define NB 2
#define NH 16
#define HDIM 128
#define MM (NB*SS)   // 4096 rows

typedef __attribute__((ext_vector_type(8))) short bf16x8;
typedef __attribute__((ext_vector_type(4))) float f32x4;
typedef __attribute__((ext_vector_type(4))) ushort u16x4;

__device__ __forceinline__ float fast_exp2(float x) {
  return __builtin_amdgcn_exp2f(x);   // v_exp_f32 (2^x natively)
}

__device__ __forceinline__ ushort f2bf(float f) {
  union { float f; uint32_t u; } v; v.f = f;
  uint32_t u = v.u;
  return (ushort)((u + 0x7fffu + ((u >> 16) & 1u)) >> 16);
}

__device__ __forceinline__ void gld_lds16(const ushort* g, ushort* l) {
  __builtin_amdgcn_global_load_lds(
      (const __attribute__((address_space(1))) void*)g,
      (__attribute__((address_space(3))) void*)l, 16, 0, 0);
}

// ---------------- fp32 -> bf16 conversion of x and the 4 weights -------------
__global__ __launch_bounds__(256) void cvt_all(
    const float* __restrict__ x, const float* __restrict__ wq,
    const float* __restrict__ wk, const float* __restrict__ wv,
    const float* __restrict__ wo, ushort* __restrict__ dst)
{
  int i8 = blockIdx.x * 256 + threadIdx.x;   // one 8-float chunk per thread
  const int X8 = MM * DD / 8;                // 1,048,576
  const int W8 = DD * DD / 8;                // 524,288
  const float* src; int off;
  if (i8 < X8)            { src = x;  off = i8; }
  else if (i8 < X8 +   W8){ src = wq; off = i8 - X8; }
  else if (i8 < X8 + 2*W8){ src = wk; off = i8 - (X8 +   W8); }
  else if (i8 < X8 + 3*W8){ src = wv; off = i8 - (X8 + 2*W8); }
  else                    { src = wo; off = i8 - (X8 + 3*W8); }
  const float4* p = (const float4*)src;
  float4 a = p[(long)off*2], b = p[(long)off*2 + 1];
  bf16x8 o;
  o[0]=(short)f2bf(a.x); o[1]=(short)f2bf(a.y); o[2]=(short)f2bf(a.z); o[3]=(short)f2bf(a.w);
  o[4]=(short)f2bf(b.x); o[5]=(short)f2bf(b.y); o[6]=(short)f2bf(b.z); o[7]=(short)f2bf(b.w);
  *(bf16x8*)(dst + (long)i8*8) = o;
}

// ---- GEMM: 256x128 tile, BK=32, 4 waves (each 128x64), TRIPLE buffer -------
// Geometry: 12 ds_read_b128 per 32 MFMA per wave (0.375 ratio) -> LDS floor
// (46us) below MFMA floor (50us). 72KB LDS -> 2 blocks/CU for cross-block
// overlap (m114). 2-ahead staging, counted vmcnt(6), never 0 in steady state.
// Paired-row LDS layout: 2 K-rows per 128B line, 8 slots, XOR (line&7) ->
// same verified conflict-free structure as BK=64 layouts.
// MODE 0: QKV fused (N=6144, 768 blocks): Q scaled, K, V transposed.
// MODE 1: O-proj (N=2048, 256 blocks): f32 out.
template<int MODE>
__global__ __launch_bounds__(256, 2) void gemm_tri(
    const ushort* __restrict__ A, const ushort* __restrict__ Bt,
    ushort* __restrict__ Qo, ushort* __restrict__ Ko, ushort* __restrict__ Vt,
    float* __restrict__ Cf)
{
  __shared__ ushort lds[3 * 12288];          // 3 x 24 KB = 72 KB
  const int t = threadIdx.x;
  const int bid = blockIdx.x;
  const int xcd = bid & 7, local = bid >> 3;
  const int NBX = (MODE == 0) ? 6 : 2;       // n-tiles per XCD chunk
  const int bm = local / NBX;
  const int bn = xcd * NBX + (local - bm * NBX);
  const int lane = t & 63, w = t >> 6;       // 4 waves
  const int wr = w >> 1, wcn = w & 1;        // 2M x 2N; per-wave 128x64
  const int lr = lane & 15, lg = lane >> 4;  // lg 0..3

  // staging chunk maps: linear LDS chunk p -> global (row, col-chunk).
  // line = p>>3, slot = p&7, sraw = slot^(line&7), row = 2*line+(sraw>>2),
  // col-chunk = sraw&3.  A: 1024 chunks (4/thread); B: 512 (2/thread).
  int aoff[4], boff[2];
#pragma unroll
  for (int i = 0; i < 4; ++i) {
    int p = i*256 + t, ln = p >> 3, sr = (p & 7) ^ (ln & 7);
    aoff[i] = (2*ln + (sr >> 2)) * DD + (sr & 3) * 8;
  }
#pragma unroll
  for (int i = 0; i < 2; ++i) {
    int p = i*256 + t, ln = p >> 3, sr = (p & 7) ^ (ln & 7);
    boff[i] = (2*ln + (sr >> 2)) * DD + (sr & 3) * 8;
  }
  const ushort* Ab = A  + (long)(bm*256) * DD;
  const ushort* Bb = Bt + (long)(bn*128) * DD;

#define STG_A01(KT, BUF) do { const ushort* g_ = Ab + (KT)*32;             \
    ushort* l_ = lds + (BUF)*12288;                                        \
    gld_lds16(g_ + aoff[0], l_ + t*8);                                     \
    gld_lds16(g_ + aoff[1], l_ + (256 + t)*8); } while (0)
#define STG_A23(KT, BUF) do { const ushort* g_ = Ab + (KT)*32;             \
    ushort* l_ = lds + (BUF)*12288;                                        \
    gld_lds16(g_ + aoff[2], l_ + (512 + t)*8);                             \
    gld_lds16(g_ + aoff[3], l_ + (768 + t)*8); } while (0)
#define STG_B(KT, BUF)   do { const ushort* g_ = Bb + (KT)*32;             \
    ushort* l_ = lds + (BUF)*12288 + 8192;                                 \
    gld_lds16(g_ + boff[0], l_ + t*8);                                     \
    gld_lds16(g_ + boff[1], l_ + (256 + t)*8); } while (0)
  // read side: row r -> line r>>1, slot (lg + 4*(r&1)) ^ (line&7)
#define LDA(dst, m) { int r_ = wr*128 + (m)*16 + lr; int ln_ = r_ >> 1;    \
    int sl_ = (lg + ((r_ & 1) << 2)) ^ (ln_ & 7);                          \
    (dst) = *(const bf16x8*)(cb + ln_*128 + sl_*16); }
#define LDB(dst, n) { int r_ = wcn*64 + (n)*16 + lr; int ln_ = r_ >> 1;    \
    int sl_ = (lg + ((r_ & 1) << 2)) ^ (ln_ & 7);                          \
    (dst) = *(const bf16x8*)(cb + 16384 + ln_*128 + sl_*16); }
#define MFMA42(AV, BV, MB, NB_) do {                                       \
    __builtin_amdgcn_s_setprio(1);                                         \
    _Pragma("unroll") for (int m = 0; m < 4; ++m)                          \
    _Pragma("unroll") for (int n = 0; n < 2; ++n)                          \
      acc[(MB)+m][(NB_)+n] = __builtin_amdgcn_mfma_f32_16x16x32_bf16(      \
          AV[m], BV[n], acc[(MB)+m][(NB_)+n], 0, 0, 0);                    \
    __builtin_amdgcn_s_setprio(0); } while (0)
#define SB  __builtin_amdgcn_sched_barrier(0)
#define BAR __builtin_amdgcn_s_barrier()
#define LGKM0 asm volatile("s_waitcnt lgkmcnt(0)" ::: "memory")

  f32x4 acc[8][4] = {};
  const int T = DD / 32;                     // 64 K-tiles

  // prologue: tiles 0,1 fully staged (6 loads each); wait tile0 (6 remain)
  STG_A01(0, 0); STG_A23(0, 0); STG_B(0, 0);
  STG_A01(1, 1); STG_A23(1, 1); STG_B(1, 1);
  asm volatile("s_waitcnt vmcnt(6)" ::: "memory");
  SB; BAR; SB;

  for (int kt = 0; kt < T; ++kt) {
    const char* cb = (const char*)lds + (kt % 3) * 24576;
    const int bs = (kt + 2) % 3;             // holds tile kt-1: fully read
    const bool st = (kt + 2 < T);
    bf16x8 a03[4], a47[4], b01[2], b23[2];
    // P1: A0-3 + B0-1 (6 reads) | stage A01 of kt+2
    LDA(a03[0],0); LDA(a03[1],1); LDA(a03[2],2); LDA(a03[3],3);
    LDB(b01[0],0); LDB(b01[1],1);
    if (st) STG_A01(kt+2, bs);
    SB; BAR; LGKM0; SB;
    MFMA42(a03, b01, 0, 0);
    SB; BAR; SB;
    // P2: A4-7 (4 reads) | stage A23
    LDA(a47[0],4); LDA(a47[1],5); LDA(a47[2],6); LDA(a47[3],7);
    if (st) STG_A23(kt+2, bs);
    SB; BAR; LGKM0; SB;
    MFMA42(a47, b01, 4, 0);
    SB; BAR; SB;
    // P3: B2-3 (2 reads) | stage B
    LDB(b23[0],2); LDB(b23[1],3);
    if (st) STG_B(kt+2, bs);
    SB; BAR; LGKM0; SB;
    MFMA42(a03, b23, 0, 2);
    SB; BAR; SB;
    // P4: counted wait: tile kt+1 landed (kt+2's 6 stay in flight)
    if (st)              { asm volatile("s_waitcnt vmcnt(6)" ::: "memory"); }
    else if (kt + 1 < T) { asm volatile("s_waitcnt vmcnt(0)" ::: "memory"); }
    SB; BAR; SB;
    MFMA42(a47, b23, 4, 2);
    SB; BAR; SB;
  }
#undef STG_A01
#undef STG_A23
#undef STG_B
#undef LDA
#undef LDB
#undef MFMA42
#undef SB
#undef BAR
#undef LGKM0

  // epilogue: C/D layout col=lane&15, row=(lane>>4)*4+j
  const int crb = bm*256 + wr*128 + lg*4;
  if (MODE == 0) {
    const int region = bn >> 4;              // 0=Q, 1=K, 2=V (16 bn each)
    const int ccb = (bn & 15)*128 + wcn*64 + lr;
    if (region < 2) {
      const float scale = (region == 0) ? (0.08838834764831845f * 1.4426950408889634f) : 1.0f;
      ushort* C = (region == 0) ? Qo : Ko;
#pragma unroll
      for (int m = 0; m < 8; ++m)
#pragma unroll
        for (int n = 0; n < 4; ++n)
#pragma unroll
          for (int j = 0; j < 4; ++j)
            C[(long)(crb + m*16 + j) * DD + (ccb + n*16)] = f2bf(acc[m][n][j] * scale);
    } else {
      // V transposed: Vt[(b*NH+h)*HDIM + d][s]; 4 j-rows = 4 contiguous s
#pragma unroll
      for (int m = 0; m < 8; ++m) {
        int sg = crb + m*16;
        int b2 = sg >> 11, s2 = sg & 2047;
#pragma unroll
        for (int n = 0; n < 4; ++n) {
          int colv = ccb + n*16;
          int h2 = colv >> 7, d2 = colv & 127;
          u16x4 pk;
          pk[0] = f2bf(acc[m][n][0]); pk[1] = f2bf(acc[m][n][1]);
          pk[2] = f2bf(acc[m][n][2]); pk[3] = f2bf(acc[m][n][3]);
          *(u16x4*)(Vt + ((long)((b2*NH + h2)*HDIM + d2)) * SS + s2) = pk;
        }
      }
    }
  } else {
    const int ccb = bn*128 + wcn*64 + lr;
#pragma unroll
    for (int m = 0; m < 8; ++m)
#pragma unroll
      for (int n = 0; n < 4; ++n)
#pragma unroll
        for (int j = 0; j < 4; ++j)
          Cf[(long)(crb + m*16 + j) * DD + (ccb + n*16)] = acc[m][n][j];
  }
}

// ---------------- causal flash attention (8 waves x 16 q-rows) ---------------
// K staged via global_load_lds with pre-swizzled source (read XOR (r&7)<<4);
// V already transposed in global -> staged the same way; no scalar transpose.
__global__ __launch_bounds__(512, 4) void attn_fwd(
    const ushort* __restrict__ Qb, const ushort* __restrict__ Kb,
    const ushort* __restrict__ Vtg, ushort* __restrict__ Ob)
{
  __shared__ ushort Ks[64*128];     // [k][d] rows 256B, XOR-swizzled chunks
  __shared__ ushort Vs[128*64];     // [d][k] rows 128B, XOR-swizzled chunks
  __shared__ ushort Ps[8*16*72];    // per-wave P [16][64], padded stride 72

  const int bid = blockIdx.x;
  const int qt = 15 - (bid >> 5);   // LPT: heaviest q-tiles first
  const int bh = bid & 31;
  const int b = bh >> 4, h = bh & 15;
  const int t = threadIdx.x;
  const int lane = t & 63;
  const int wq = t >> 6;            // 0..7
  const int lr = lane & 15, lg = lane >> 4;

  const int qbase = qt * 128;
  const long rowQ = (long)(b * SS + qbase + wq * 16);

  bf16x8 qf[4];                     // Q rows of this wave, pre-scaled
#pragma unroll
  for (int c = 0; c < 4; ++c)
    qf[c] = *(const bf16x8*)(Qb + (rowQ + lr) * DD + h*HDIM + c*32 + lg*8);

  f32x4 accO[8] = {};
  float mrow[4], lrow[4];
#pragma unroll
  for (int j = 0; j < 4; ++j) { mrow[j] = -1e30f; lrow[j] = 0.f; }

  // K staging: 1024 16B-chunks; thread t owns chunks t and 512+t
  const ushort* Kgb = Kb + (long)(b * SS) * DD + h * HDIM;
  const int kr0 = t >> 4, kr1 = 32 + (t >> 4), kci = t & 15;
  const ushort* gk0 = Kgb + (long)kr0 * DD + (kci ^ (kr0 & 7)) * 8;
  const ushort* gk1 = Kgb + (long)kr1 * DD + (kci ^ (kr1 & 7)) * 8;
  ushort* lk0 = Ks + t*8;
  ushort* lk1 = Ks + 4096 + t*8;

  // V^T staging: rows d (128B), 8 chunks each
  const ushort* Vgb = Vtg + (long)(bh * HDIM) * SS;
  const int vd0 = t >> 3, vd1 = 64 + (t >> 3), vci = t & 7;
  const ushort* gv0 = Vgb + (long)vd0 * SS + (vci ^ (vd0 & 7)) * 8;
  const ushort* gv1 = Vgb + (long)vd1 * SS + (vci ^ (vd1 & 7)) * 8;
  ushort* lv0 = Vs + t*8;
  ushort* lv1 = Vs + 4096 + t*8;

  const int ktmax = 2*qt + 1;
  const int qminw = qbase + wq*16;        // wave's FIRST q-row (mask trigger)
  const int qmaxw = qminw + 15;           // wave's last q-row (skip test)
  ushort* myP = Ps + wq * (16*72);

  for (int kt = 0; kt <= ktmax; ++kt) {
    const int k0 = kt * 64;
    gld_lds16(gk0, lk0); gld_lds16(gk1, lk1);
    gld_lds16(gv0, lv0); gld_lds16(gv1, lv1);
    gk0 += (long)64 * DD; gk1 += (long)64 * DD;
    gv0 += 64; gv1 += 64;
    __syncthreads();                 // drains vmcnt -> LDS tiles ready

    if (k0 <= qmaxw) {
      f32x4 sc[4] = {};
#pragma unroll
      for (int n = 0; n < 4; ++n) {  // S = Q K^T (this wave's 16 q-rows)
        int r = n*16 + lr;
        int swz = (r & 7) << 4;
#pragma unroll
        for (int c = 0; c < 4; ++c) {
          bf16x8 kf = *(const bf16x8*)((const char*)Ks + ((r*256 + c*64 + lg*16) ^ swz));
          sc[n] = __builtin_amdgcn_mfma_f32_16x16x32_bf16(qf[c], kf, sc[n], 0,0,0);
        }
      }
      if (k0 + 63 > qminw) {         // tile has keys beyond wave's FIRST row
#pragma unroll
        for (int n = 0; n < 4; ++n)
#pragma unroll
          for (int j = 0; j < 4; ++j) {
            int kpos = k0 + n*16 + lr;
            int qpos = qminw + lg*4 + j;
            if (kpos > qpos) sc[n][j] = -1e30f;
          }
      }
      float al[4];
#pragma unroll
      for (int j = 0; j < 4; ++j) {  // online softmax in log2 domain
        float tm = fmaxf(fmaxf(sc[0][j], sc[1][j]), fmaxf(sc[2][j], sc[3][j]));
#pragma unroll
        for (int off = 1; off < 16; off <<= 1) tm = fmaxf(tm, __shfl_xor(tm, off));
        float mn = fmaxf(mrow[j], tm);
        float a = fast_exp2(mrow[j] - mn);
        mrow[j] = mn;
        float ts = 0.f;
#pragma unroll
        for (int n = 0; n < 4; ++n) {
          float p = fast_exp2(sc[n][j] - mn);
          sc[n][j] = p; ts += p;
        }
#pragma unroll
        for (int off = 1; off < 16; off <<= 1) ts += __shfl_xor(ts, off);
        lrow[j] = lrow[j] * a + ts;
        al[j] = a;
      }
#pragma unroll
      for (int dg = 0; dg < 8; ++dg) {
        f32x4 v = accO[dg];
        v[0] *= al[0]; v[1] *= al[1]; v[2] *= al[2]; v[3] *= al[3];
        accO[dg] = v;
      }
#pragma unroll
      for (int n = 0; n < 4; ++n)    // P -> per-wave LDS (D-layout -> A-layout)
#pragma unroll
        for (int j = 0; j < 4; ++j)
          myP[(lg*4 + j)*72 + n*16 + lr] = f2bf(sc[n][j]);
      bf16x8 pa0 = *(const bf16x8*)(myP + lr*72 + lg*8);
      bf16x8 pa1 = *(const bf16x8*)(myP + lr*72 + 32 + lg*8);
#pragma unroll
      for (int dg = 0; dg < 8; ++dg) {   // O += P V
        int d = dg*16 + lr;
        int vswz = (d & 7) << 4;
        bf16x8 v0 = *(const bf16x8*)((const char*)Vs + ((d*128 + lg*16) ^ vswz));
        bf16x8 v1 = *(const bf16x8*)((const char*)Vs + ((d*128 + 64 + lg*16) ^ vswz));
        accO[dg] = __builtin_amdgcn_mfma_f32_16x16x32_bf16(pa0, v0, accO[dg], 0,0,0);
        accO[dg] = __builtin_amdgcn_mfma_f32_16x16x32_bf16(pa1, v1, accO[dg], 0,0,0);
      }
    }
    __syncthreads();                 // reads done before restage
  }

  float inv[4];
#pragma unroll
  for (int j = 0; j < 4; ++j) inv[j] = 1.0f / lrow[j];
  ushort* Og = Ob + rowQ * DD + h * HDIM;
#pragma unroll
  for (int dg = 0; dg < 8; ++dg)
#pragma unroll
    for (int j = 0; j < 4; ++j)
      Og[(long)(lg*4 + j) * DD + dg*16 + lr] = f2bf(accO[dg][j] * inv[j]);
}

// ---------------- launch ----------------------------------------------------
extern "C" void kernel_launch(void* const* d_in, const int* in_sizes, int n_in,
                              void* d_out, int out_size, void* d_ws, size_t ws_size,
                              hipStream_t stream) {
  const float* x  = (const float*)d_in[0];
  const float* Wq = (const float*)d_in[1];
  const float* Wk = (const float*)d_in[2];
  const float* Wv = (const float*)d_in[3];
  const float* Wo = (const float*)d_in[4];

  ushort* ws  = (ushort*)d_ws;
  ushort* xb  = ws;                         // x bf16; later reused as attn-out
  ushort* wqb = ws  + (long)MM*DD;          // wq/wk/wv contiguous = fused Bt
  ushort* wkb = wqb + (long)DD*DD;
  ushort* wvb = wkb + (long)DD*DD;
  ushort* wob = wvb + (long)DD*DD;
  ushort* Qb  = wob + (long)DD*DD;
  ushort* Kb  = Qb  + (long)MM*DD;
  ushort* Vtg = Kb  + (long)MM*DD;          // V stored transposed [bh*128+d][s]
  (void)wkb; (void)wvb;

  const int CVT_BLOCKS = (MM*DD + 4*DD*DD) / 8 / 256;   // 12288
  cvt_all<<<CVT_BLOCKS, 256, 0, stream>>>(x, Wq, Wk, Wv, Wo, ws);

  gemm_tri<0><<<768, 256, 0, stream>>>(xb, wqb, Qb, Kb, Vtg, nullptr);

  attn_fwd<<<512, 512, 0, stream>>>(Qb, Kb, Vtg, xb);   // attn out -> xb

  gemm_tri<1><<<256, 256, 0, stream>>>(xb, wob, nullptr, nullptr, nullptr,
                                       (float*)d_out);
}